// Round 1
// baseline (139.976 us; speedup 1.0000x reference)
//
#include <hip/hip_runtime.h>
#include <hip/hip_bf16.h>

typedef __attribute__((ext_vector_type(8))) short short8;   // 8 x bf16
typedef __attribute__((ext_vector_type(4))) float f32x4;

#define MFMA16(a, b, c) __builtin_amdgcn_mfma_f32_16x16x32_bf16((a), (b), (c), 0, 0, 0)

__device__ __forceinline__ unsigned short f2bf(float f) {
    unsigned u = __builtin_bit_cast(unsigned, f);
    u += 0x7FFFu + ((u >> 16) & 1u);          // RNE
    return (unsigned short)(u >> 16);
}

__device__ __forceinline__ short8 pack8(float4 a, float4 b) {
    short8 r;
    r[0] = (short)f2bf(a.x); r[1] = (short)f2bf(a.y);
    r[2] = (short)f2bf(a.z); r[3] = (short)f2bf(a.w);
    r[4] = (short)f2bf(b.x); r[5] = (short)f2bf(b.y);
    r[6] = (short)f2bf(b.z); r[7] = (short)f2bf(b.w);
    return r;
}

// key_pe: [64][1024] f32  ->  PET: [1024][64] bf16
__global__ void pe_transpose_kernel(const float* __restrict__ pe,
                                    unsigned short* __restrict__ pet) {
    int idx = blockIdx.x * 256 + threadIdx.x;     // 65536 total
    int l = idx >> 6, h = idx & 63;
    pet[idx] = f2bf(pe[(h << 10) | l]);
}

// B=128 (batch*head), M=512, L=1024, H=64, key len = 1536
// WG: 4 waves, each wave owns 16 query rows. 17 absolute key-blocks of 64.
__global__ __launch_bounds__(256, 3) void attn_kernel(
    const float* __restrict__ Qg, const float* __restrict__ Kg,
    const float* __restrict__ Vg, const unsigned short* __restrict__ PET,
    const float* __restrict__ SPAN, float* __restrict__ OUT)
{
    __shared__ unsigned short Klds[64 * 72];      // [key][h], stride 72
    __shared__ unsigned short Vlds[64 * 72];      // [h][key], stride 72 (transposed)
    __shared__ unsigned short Wlds[4][16 * 72];   // per-wave weights round-trip

    const int bid = blockIdx.x;
    const int b  = (bid & 7) * 16 + (bid >> 6);   // XCD-swizzle: same-b WGs share an XCD
    const int qt = (bid >> 3) & 7;
    const int i0 = qt << 6;

    const int tid  = threadIdx.x;
    const int w    = tid >> 6;
    const int lane = tid & 63;
    const int c16  = lane & 15;
    const int g    = lane >> 4;

    float z = SPAN[b & 15];
    z = fminf(fmaxf(z, 0.0f), 1.0f);
    const float zc = z * 32.0f + 1.0f;            // z*L/RAMP + 1

    // Q A-frags: row = lane&15, k = g*8 + j (+32 for frag1)
    short8 qf0, qf1;
    {
        const float* qp = Qg + ((size_t)(b * 512 + i0 + w * 16 + c16) * 64 + g * 8);
        qf0 = pack8(*(const float4*)qp,        *(const float4*)(qp + 4));
        qf1 = pack8(*(const float4*)(qp + 32), *(const float4*)(qp + 36));
    }

    const f32x4 zero = {0.f, 0.f, 0.f, 0.f};
    f32x4 Oacc[4];
#pragma unroll
    for (int t = 0; t < 4; ++t) Oacc[t] = zero;
    f32x4 sumw = zero, sume = zero;

    const int d0w_off = -(w << 4);

    for (int dblk = 0; dblk < 17; ++dblk) {
        const int d = dblk << 6;
        __syncthreads();
        // ---- stage K block (64 keys x 64 h) as bf16, [key][h] ----
        {
            const int row = tid >> 2, h0 = (tid & 3) << 4;
            const float* kp = Kg + ((size_t)(b * 1536 + i0 + d + row) * 64 + h0);
            float4 k0 = ((const float4*)kp)[0];
            float4 k1 = ((const float4*)kp)[1];
            float4 k2 = ((const float4*)kp)[2];
            float4 k3 = ((const float4*)kp)[3];
            *(short8*)&Klds[row * 72 + h0]     = pack8(k0, k1);
            *(short8*)&Klds[row * 72 + h0 + 8] = pack8(k2, k3);
        }
        // ---- stage V block transposed: Vlds[h][key], packed pair writes ----
        {
            const int j0 = (tid & 31) << 1, h0 = (tid >> 5) << 3;
            const float* vp = Vg + ((size_t)(b * 1536 + i0 + d + j0) * 64 + h0);
            float4 a0 = ((const float4*)vp)[0];
            float4 a1 = ((const float4*)vp)[1];
            float4 b0 = ((const float4*)(vp + 64))[0];
            float4 b1 = ((const float4*)(vp + 64))[1];
            float ta[8] = {a0.x, a0.y, a0.z, a0.w, a1.x, a1.y, a1.z, a1.w};
            float tb[8] = {b0.x, b0.y, b0.z, b0.w, b1.x, b1.y, b1.z, b1.w};
#pragma unroll
            for (int u = 0; u < 8; ++u) {
                unsigned pv = (unsigned)f2bf(ta[u]) | ((unsigned)f2bf(tb[u]) << 16);
                *(unsigned*)&Vlds[(h0 + u) * 72 + j0] = pv;
            }
        }
        __syncthreads();

        const int d0w = d + d0w_off;      // key-block offset relative to this wave's rows
        const int lb  = d0w - 16;         // PE strip base (5 tiles of 16 cover jj-ii shifts)

        // ---- positional strip: Sp[tt] = Q · PE^T over l = lb + tt*16 + col ----
        f32x4 Sp[5];
#pragma unroll
        for (int tt = 0; tt < 5; ++tt) {
            int lr = lb + (tt << 4) + c16;
            lr = lr < 0 ? 0 : (lr > 1023 ? 1023 : lr);   // clamped rows are masked later
            const unsigned short* pp = PET + ((lr << 6) + (g << 3));
            short8 p0 = *(const short8*)pp;
            short8 p1 = *(const short8*)(pp + 32);
            f32x4 acc = zero;
            acc = MFMA16(qf0, p0, acc);
            acc = MFMA16(qf1, p1, acc);
            Sp[tt] = acc;
        }

        // ---- content scores: Sc[jc] = Q · K_block^T ----
        f32x4 Sc[4];
#pragma unroll
        for (int jc = 0; jc < 4; ++jc) {
            const unsigned short* kb = &Klds[(jc * 16 + c16) * 72 + (g << 3)];
            short8 k0 = *(const short8*)kb;
            short8 k1 = *(const short8*)(kb + 32);
            f32x4 acc = zero;
            acc = MFMA16(qf0, k0, acc);
            acc = MFMA16(qf1, k1, acc);
            Sc[jc] = acc;
        }

        // ---- combine + exp + span mask, write W (bf16) for PV ----
        unsigned short* Wp = Wlds[w];
#pragma unroll
        for (int jc = 0; jc < 4; ++jc) {
#pragma unroll
            for (int r = 0; r < 4; ++r) {
                const int ii    = (g << 2) + r;
                const int delta = c16 - ii;
                const int src   = (lane & 48) | (delta & 15);
                const float pa  = __shfl(Sp[jc][r],     src, 64);
                const float pb  = __shfl(Sp[jc + 1][r], src, 64);
                const float pe  = (delta >= 0) ? pb : pa;
                const int l     = d0w + (jc << 4) + delta;   // relative position
                const float sv  = (Sc[jc][r] + pe) * 0.125f;
                const float e   = __expf(sv);
                const bool valid = ((unsigned)l < 1024u);
                float msk = (float)(l - 1023) * 0.03125f + zc;
                msk = fminf(fmaxf(msk, 0.0f), 1.0f);
                const float wgt = valid ? e * msk : 0.0f;
                sumw[r] += wgt;
                sume[r] += valid ? e : 0.0f;
                Wp[ii * 72 + (jc << 4) + c16] = f2bf(wgt);
            }
        }

        // ---- PV: Oacc += W · V_block ----
        short8 wf0 = *(const short8*)&Wp[c16 * 72 + (g << 3)];
        short8 wf1 = *(const short8*)&Wp[c16 * 72 + 32 + (g << 3)];
#pragma unroll
        for (int ht = 0; ht < 4; ++ht) {
            const unsigned short* vb = &Vlds[(ht * 16 + c16) * 72 + (g << 3)];
            short8 v0 = *(const short8*)vb;
            short8 v1 = *(const short8*)(vb + 32);
            Oacc[ht] = MFMA16(wf0, v0, Oacc[ht]);
            Oacc[ht] = MFMA16(wf1, v1, Oacc[ht]);
        }
    }

    // ---- epilogue: renormalize and store ----
#pragma unroll
    for (int r = 0; r < 4; ++r) {
        float sw = sumw[r], se = sume[r];
#pragma unroll
        for (int m = 1; m < 16; m <<= 1) {
            sw += __shfl_xor(sw, m, 64);
            se += __shfl_xor(se, m, 64);
        }
        const float inv = 1.0f / (sw + 1e-8f * se);
        float* op = OUT + ((size_t)(b * 512 + i0 + w * 16 + (g << 2) + r) * 64);
#pragma unroll
        for (int ht = 0; ht < 4; ++ht)
            op[ht * 16 + c16] = Oacc[ht][r] * inv;
    }
}

extern "C" void kernel_launch(void* const* d_in, const int* in_sizes, int n_in,
                              void* d_out, int out_size, void* d_ws, size_t ws_size,
                              hipStream_t stream) {
    const float* Q    = (const float*)d_in[0];
    const float* K    = (const float*)d_in[1];
    const float* V    = (const float*)d_in[2];
    const float* PE   = (const float*)d_in[3];
    const float* SPAN = (const float*)d_in[4];
    unsigned short* PET = (unsigned short*)d_ws;   // 1024*64 bf16 = 128 KiB

    pe_transpose_kernel<<<256, 256, 0, stream>>>(PE, PET);
    attn_kernel<<<1024, 256, 0, stream>>>(Q, K, V, PET, SPAN, (float*)d_out);
}

// Round 2
// 119.503 us; speedup vs baseline: 1.1713x; 1.1713x over previous
//
#include <hip/hip_runtime.h>
#include <hip/hip_bf16.h>

typedef __attribute__((ext_vector_type(8))) short short8;   // 8 x bf16
typedef __attribute__((ext_vector_type(4))) float f32x4;

#define MFMA16(a, b, c) __builtin_amdgcn_mfma_f32_16x16x32_bf16((a), (b), (c), 0, 0, 0)

__device__ __forceinline__ unsigned short f2bf(float f) {       // RNE
    unsigned u = __builtin_bit_cast(unsigned, f);
    u += 0x7FFFu + ((u >> 16) & 1u);
    return (unsigned short)(u >> 16);
}
__device__ __forceinline__ unsigned short bfc(float f) {        // cheap round
    return (unsigned short)((__builtin_bit_cast(unsigned, f) + 0x8000u) >> 16);
}

__device__ __forceinline__ short8 pack8(float4 a, float4 b) {
    short8 r;
    r[0] = (short)f2bf(a.x); r[1] = (short)f2bf(a.y);
    r[2] = (short)f2bf(a.z); r[3] = (short)f2bf(a.w);
    r[4] = (short)f2bf(b.x); r[5] = (short)f2bf(b.y);
    r[6] = (short)f2bf(b.z); r[7] = (short)f2bf(b.w);
    return r;
}

__device__ __forceinline__ void stage16(const void* g, void* l) {
    __builtin_amdgcn_global_load_lds((const __attribute__((address_space(1))) void*)g,
                                     (__attribute__((address_space(3))) void*)l, 16, 0, 0);
}

// ---------------- pre-kernels ----------------

// key_pe: [64][1024] f32  ->  PET: [1024][64] bf16
__global__ void pe_transpose_kernel(const float* __restrict__ pe,
                                    unsigned short* __restrict__ pet) {
    int idx = blockIdx.x * 256 + threadIdx.x;     // 65536
    int l = idx >> 6, h = idx & 63;
    pet[idx] = f2bf(pe[(h << 10) | l]);
}

// K [128][1536][64] f32 -> Kws bf16, elem e stored from e^((j&7)<<3)  (pre-swizzle)
__global__ void convK_kernel(const float* __restrict__ K, unsigned short* __restrict__ Kws) {
    int idx = blockIdx.x * 256 + threadIdx.x;     // 1,572,864
    int jl = idx >> 3;                            // b*1536 + j
    int e0 = (idx & 7) << 3;
    int x  = (jl & 7) << 3;
    const float* src = K + ((size_t)jl << 6) + (e0 ^ x);
    float4 a = ((const float4*)src)[0], b = ((const float4*)src)[1];
    *(short8*)(Kws + ((size_t)jl << 6) + e0) = pack8(a, b);
}

// V [128][1536][64] f32 -> Vws [b][blk(24)][h(64)][kk(64)] bf16 transposed,
// kk stored from kk^((h&7)<<3) (pre-swizzle). LDS-tile transpose for coalescing.
__global__ void convV_kernel(const float* __restrict__ V, unsigned short* __restrict__ Vws) {
    __shared__ unsigned short T[64][72];          // [j][h] bf16
    int b = blockIdx.y, blk = blockIdx.x, tid = threadIdx.x;
    {
        int j = tid >> 2, h0 = (tid & 3) << 4;
        const float* src = V + ((size_t)(b * 1536 + blk * 64 + j) << 6) + h0;
        float4 a0 = ((const float4*)src)[0], a1 = ((const float4*)src)[1];
        float4 a2 = ((const float4*)src)[2], a3 = ((const float4*)src)[3];
        *(short8*)&T[j][h0]     = pack8(a0, a1);
        *(short8*)&T[j][h0 + 8] = pack8(a2, a3);
    }
    __syncthreads();
    {
        int h = tid & 63, k0 = (tid >> 6) << 4;   // 16 keys per thread
        int x = (h & 7) << 3;
        unsigned short* dst = Vws + ((size_t)(b * 24 + blk) << 12) + (h << 6) + k0;
        short8 o0, o1;
#pragma unroll
        for (int u = 0; u < 8; ++u) o0[u] = (short)T[(k0 + u) ^ x][h];
#pragma unroll
        for (int u = 0; u < 8; ++u) o1[u] = (short)T[(k0 + 8 + u) ^ x][h];
        ((short8*)dst)[0] = o0;
        ((short8*)dst)[1] = o1;
    }
}

// ---------------- main kernel (v2) ----------------
// B=128, M=512, L=1024, H=64, KV=1536. 1024 WGs x 4 waves, 16 q-rows/wave.
__global__ __launch_bounds__(256, 4) void attn_v2(
    const float* __restrict__ Qg, const unsigned short* __restrict__ Kws,
    const unsigned short* __restrict__ Vws, const unsigned short* __restrict__ PET,
    const float* __restrict__ SPAN, float* __restrict__ OUT)
{
    __shared__ unsigned short Klds[2][4096];      // [buf][j*64 + e]  (8 KB each)
    __shared__ unsigned short Vlds[2][4096];      // [buf][h*64 + kk] (8 KB each)
    __shared__ unsigned short Wlds[4][1024];      // per-wave 16x64, XOR-swizzled

    const int bid = blockIdx.x;
    const int b   = (bid & 7) * 16 + (bid >> 6);  // XCD swizzle
    const int i0  = ((bid >> 3) & 7) << 6;
    const int tid = threadIdx.x, w = tid >> 6, lane = tid & 63;
    const int c16 = lane & 15, g = lane >> 4;

    float z = SPAN[b & 15];
    z = fminf(fmaxf(z, 0.f), 1.f);
    const float mc = z * 32.f + 1.f - 1023.f * 0.03125f;   // msk = clamp(l/32 + mc, 0, 1)

    short8 qf0, qf1;
    {
        const float* qp = Qg + ((size_t)((b << 9) + i0 + (w << 4) + c16) << 6) + (g << 3);
        qf0 = pack8(*(const float4*)qp,        *(const float4*)(qp + 4));
        qf1 = pack8(*(const float4*)(qp + 32), *(const float4*)(qp + 36));
    }

    const f32x4 zero = {0.f, 0.f, 0.f, 0.f};
    f32x4 Oacc[4] = {zero, zero, zero, zero};
    f32x4 sumw = zero, sume = zero;
    f32x4 Sp[5];

    const char* kbase = (const char*)Kws + (((size_t)b * 1536 + i0) << 7);
    const char* vbase = (const char*)Vws + (((size_t)b * 24 + (i0 >> 6)) << 13);
    const int ubase = w << 10;                     // wave-uniform byte off in 8KB block
    const int loff  = ubase + lane * 16;           // per-lane global byte off

#define STAGE(bufi, t) do {                                                    \
        const char* kg_ = kbase + (t) * 8192 + loff;                           \
        const char* vg_ = vbase + (t) * 8192 + loff;                           \
        unsigned short* kl_ = &Klds[bufi][ubase >> 1];                         \
        unsigned short* vl_ = &Vlds[bufi][ubase >> 1];                         \
        stage16(kg_, kl_); stage16(kg_ + 4096, kl_ + 2048);                    \
        stage16(vg_, vl_); stage16(vg_ + 4096, vl_ + 2048);                    \
    } while (0)

#define STRIP(dst, lbase) do {                                                 \
        int lr_ = (lbase) + c16;                                               \
        lr_ = lr_ < 0 ? 0 : (lr_ > 1023 ? 1023 : lr_);                         \
        const unsigned short* pp_ = PET + ((lr_ << 6) + (g << 3));             \
        short8 p0_ = *(const short8*)pp_;                                      \
        short8 p1_ = *(const short8*)(pp_ + 32);                               \
        f32x4 a_ = MFMA16(qf0, p0_, zero);                                     \
        dst = MFMA16(qf1, p1_, a_);                                            \
    } while (0)

    STAGE(0, 0);
    { const int lb0 = -(w << 4) - 16; STRIP(Sp[4], lb0); }    // becomes Sp[0] at t=0

    for (int t = 0; t < 17; ++t) {
        const int buf = t & 1;
        __syncthreads();                           // drains stage(t); waves done with buf^1
        if (t < 16) STAGE(buf ^ 1, t + 1);         // prefetch overlaps compute(t)

        const int d   = t << 6;
        const int d0w = d - (w << 4);
        const int lb  = d0w - 16;

        // ---- positional strips (rolling reuse) ----
        Sp[0] = Sp[4];
        STRIP(Sp[1], lb + 16);
        STRIP(Sp[2], lb + 32);
        STRIP(Sp[3], lb + 48);
        STRIP(Sp[4], lb + 64);

        // ---- content scores ----
        f32x4 Sc[4];
        const int xk = (c16 & 7) << 3;
#pragma unroll
        for (int jc = 0; jc < 4; ++jc) {
            const unsigned short* p = &Klds[buf][(jc * 16 + c16) << 6];
            short8 k0 = *(const short8*)(p + ((g << 3) ^ xk));
            short8 k1 = *(const short8*)(p + (((g << 3) + 32) ^ xk));
            f32x4 a = MFMA16(qf0, k0, zero);
            Sc[jc] = MFMA16(qf1, k1, a);
        }

        // ---- combine + exp + span mask -> W (bf16, swizzled) ----
        unsigned short* Wp = &Wlds[w][0];
#pragma unroll
        for (int r = 0; r < 4; ++r) {
            const int ii    = (g << 2) + r;
            const int delta = c16 - ii;
            const int src   = (lane & 48) | (delta & 15);
            float sh0 = __shfl(Sp[0][r], src, 64);
            float sh1 = __shfl(Sp[1][r], src, 64);
            float sh2 = __shfl(Sp[2][r], src, 64);
            float sh3 = __shfl(Sp[3][r], src, 64);
            float sh4 = __shfl(Sp[4][r], src, 64);
            const bool lo = delta < 0;
            const int xw = (ii & 7) << 3;
            const float fd = (float)(d0w + delta);
#pragma unroll
            for (int jc = 0; jc < 4; ++jc) {
                float pa, pb;
                if (jc == 0) { pa = sh0; pb = sh1; }
                else if (jc == 1) { pa = sh1; pb = sh2; }
                else if (jc == 2) { pa = sh2; pb = sh3; }
                else { pa = sh3; pb = sh4; }
                const float pe = lo ? pa : pb;
                const float e  = __expf((Sc[jc][r] + pe) * 0.125f);
                const int   l  = d0w + (jc << 4) + delta;
                float msk = fminf(fmaxf(fmaf(fd + (float)(jc << 4) - fd + (float)l - (float)l,
                                             0.f, fmaf((float)l, 0.03125f, mc)), 0.f), 1.f);
                const float em  = ((unsigned)l < 1024u) ? e : 0.f;
                const float wgt = em * msk;
                sumw[r] += wgt;
                sume[r] += em;
                Wp[(ii << 6) + (((jc << 4) + c16) ^ xw)] = bfc(wgt);
            }
        }

        // ---- PV ----
        const int xr = (c16 & 7) << 3;
        const unsigned short* wrow = Wp + (c16 << 6);
        short8 wf0 = *(const short8*)(wrow + ((g << 3) ^ xr));
        short8 wf1 = *(const short8*)(wrow + (((g << 3) + 32) ^ xr));
#pragma unroll
        for (int ht = 0; ht < 4; ++ht) {
            const unsigned short* vr = &Vlds[buf][(ht * 16 + c16) << 6];
            short8 v0 = *(const short8*)(vr + ((g << 3) ^ xr));
            short8 v1 = *(const short8*)(vr + (((g << 3) + 32) ^ xr));
            f32x4 a = MFMA16(wf0, v0, Oacc[ht]);
            Oacc[ht] = MFMA16(wf1, v1, a);
        }
    }

    // ---- epilogue ----
#pragma unroll
    for (int r = 0; r < 4; ++r) {
        float sw = sumw[r], se = sume[r];
#pragma unroll
        for (int m = 1; m < 16; m <<= 1) {
            sw += __shfl_xor(sw, m, 64);
            se += __shfl_xor(se, m, 64);
        }
        const float inv = 1.0f / (sw + 1e-8f * se);
        float* op = OUT + ((size_t)((b << 9) + i0 + (w << 4) + (g << 2) + r) << 6);
#pragma unroll
        for (int ht = 0; ht < 4; ++ht)
            op[ht * 16 + c16] = Oacc[ht][r] * inv;
    }
#undef STAGE
#undef STRIP
}

// ---------------- fallback (round-1 kernel, used if ws too small) ----------------
__global__ __launch_bounds__(256, 4) void attn_v1(
    const float* __restrict__ Qg, const float* __restrict__ Kg,
    const float* __restrict__ Vg, const unsigned short* __restrict__ PET,
    const float* __restrict__ SPAN, float* __restrict__ OUT)
{
    __shared__ unsigned short Klds[64 * 72];
    __shared__ unsigned short Vlds[64 * 72];
    __shared__ unsigned short Wlds[4][16 * 72];

    const int bid = blockIdx.x;
    const int b  = (bid & 7) * 16 + (bid >> 6);
    const int qt = (bid >> 3) & 7;
    const int i0 = qt << 6;
    const int tid = threadIdx.x, w = tid >> 6, lane = tid & 63;
    const int c16 = lane & 15, g = lane >> 4;

    float z = SPAN[b & 15];
    z = fminf(fmaxf(z, 0.0f), 1.0f);
    const float zc = z * 32.0f + 1.0f;

    short8 qf0, qf1;
    {
        const float* qp = Qg + ((size_t)(b * 512 + i0 + w * 16 + c16) * 64 + g * 8);
        qf0 = pack8(*(const float4*)qp,        *(const float4*)(qp + 4));
        qf1 = pack8(*(const float4*)(qp + 32), *(const float4*)(qp + 36));
    }
    const f32x4 zero = {0.f, 0.f, 0.f, 0.f};
    f32x4 Oacc[4] = {zero, zero, zero, zero};
    f32x4 sumw = zero, sume = zero;
    const int d0w_off = -(w << 4);

    for (int dblk = 0; dblk < 17; ++dblk) {
        const int d = dblk << 6;
        __syncthreads();
        {
            const int row = tid >> 2, h0 = (tid & 3) << 4;
            const float* kp = Kg + ((size_t)(b * 1536 + i0 + d + row) * 64 + h0);
            float4 k0 = ((const float4*)kp)[0], k1 = ((const float4*)kp)[1];
            float4 k2 = ((const float4*)kp)[2], k3 = ((const float4*)kp)[3];
            *(short8*)&Klds[row * 72 + h0]     = pack8(k0, k1);
            *(short8*)&Klds[row * 72 + h0 + 8] = pack8(k2, k3);
        }
        {
            const int j0 = (tid & 31) << 1, h0 = (tid >> 5) << 3;
            const float* vp = Vg + ((size_t)(b * 1536 + i0 + d + j0) * 64 + h0);
            float4 a0 = ((const float4*)vp)[0], a1 = ((const float4*)vp)[1];
            float4 b0 = ((const float4*)(vp + 64))[0], b1 = ((const float4*)(vp + 64))[1];
            float ta[8] = {a0.x, a0.y, a0.z, a0.w, a1.x, a1.y, a1.z, a1.w};
            float tb[8] = {b0.x, b0.y, b0.z, b0.w, b1.x, b1.y, b1.z, b1.w};
#pragma unroll
            for (int u = 0; u < 8; ++u) {
                unsigned pv = (unsigned)f2bf(ta[u]) | ((unsigned)f2bf(tb[u]) << 16);
                *(unsigned*)&Vlds[(h0 + u) * 72 + j0] = pv;
            }
        }
        __syncthreads();

        const int d0w = d + d0w_off;
        const int lb  = d0w - 16;
        f32x4 Sp[5];
#pragma unroll
        for (int tt = 0; tt < 5; ++tt) {
            int lr = lb + (tt << 4) + c16;
            lr = lr < 0 ? 0 : (lr > 1023 ? 1023 : lr);
            const unsigned short* pp = PET + ((lr << 6) + (g << 3));
            short8 p0 = *(const short8*)pp;
            short8 p1 = *(const short8*)(pp + 32);
            f32x4 acc = MFMA16(qf0, p0, zero);
            Sp[tt] = MFMA16(qf1, p1, acc);
        }
        f32x4 Sc[4];
#pragma unroll
        for (int jc = 0; jc < 4; ++jc) {
            const unsigned short* kb = &Klds[(jc * 16 + c16) * 72 + (g << 3)];
            short8 k0 = *(const short8*)kb;
            short8 k1 = *(const short8*)(kb + 32);
            f32x4 acc = MFMA16(qf0, k0, zero);
            Sc[jc] = MFMA16(qf1, k1, acc);
        }
        unsigned short* Wp = Wlds[w];
#pragma unroll
        for (int jc = 0; jc < 4; ++jc) {
#pragma unroll
            for (int r = 0; r < 4; ++r) {
                const int ii    = (g << 2) + r;
                const int delta = c16 - ii;
                const int src   = (lane & 48) | (delta & 15);
                const float pa  = __shfl(Sp[jc][r],     src, 64);
                const float pb  = __shfl(Sp[jc + 1][r], src, 64);
                const float pe  = (delta >= 0) ? pb : pa;
                const int l     = d0w + (jc << 4) + delta;
                const float sv  = (Sc[jc][r] + pe) * 0.125f;
                const float e   = __expf(sv);
                const bool valid = ((unsigned)l < 1024u);
                float msk = (float)(l - 1023) * 0.03125f + zc;
                msk = fminf(fmaxf(msk, 0.0f), 1.0f);
                const float wgt = valid ? e * msk : 0.0f;
                sumw[r] += wgt;
                sume[r] += valid ? e : 0.0f;
                Wp[ii * 72 + (jc << 4) + c16] = f2bf(wgt);
            }
        }
        short8 wf0 = *(const short8*)&Wp[c16 * 72 + (g << 3)];
        short8 wf1 = *(const short8*)&Wp[c16 * 72 + 32 + (g << 3)];
#pragma unroll
        for (int ht = 0; ht < 4; ++ht) {
            const unsigned short* vb = &Vlds[(ht * 16 + c16) * 72 + (g << 3)];
            short8 v0 = *(const short8*)vb;
            short8 v1 = *(const short8*)(vb + 32);
            f32x4 a = MFMA16(wf0, v0, Oacc[ht]);
            Oacc[ht] = MFMA16(wf1, v1, a);
        }
    }
#pragma unroll
    for (int r = 0; r < 4; ++r) {
        float sw = sumw[r], se = sume[r];
#pragma unroll
        for (int m = 1; m < 16; m <<= 1) {
            sw += __shfl_xor(sw, m, 64);
            se += __shfl_xor(se, m, 64);
        }
        const float inv = 1.0f / (sw + 1e-8f * se);
        float* op = OUT + ((size_t)(b * 512 + i0 + w * 16 + (g << 2) + r) * 64);
#pragma unroll
        for (int ht = 0; ht < 4; ++ht)
            op[ht * 16 + c16] = Oacc[ht][r] * inv;
    }
}

extern "C" void kernel_launch(void* const* d_in, const int* in_sizes, int n_in,
                              void* d_out, int out_size, void* d_ws, size_t ws_size,
                              hipStream_t stream) {
    const float* Q    = (const float*)d_in[0];
    const float* K    = (const float*)d_in[1];
    const float* V    = (const float*)d_in[2];
    const float* PE   = (const float*)d_in[3];
    const float* SPAN = (const float*)d_in[4];

    const size_t VWS_BYTES = (size_t)128 * 24 * 4096 * 2;     // 25,165,824
    const size_t KWS_BYTES = (size_t)128 * 1536 * 64 * 2;     // 25,165,824
    const size_t PET_BYTES = (size_t)1024 * 64 * 2;           // 131,072
    const size_t NEED = VWS_BYTES + KWS_BYTES + PET_BYTES;

    if (ws_size >= NEED) {
        unsigned short* Vws = (unsigned short*)d_ws;
        unsigned short* Kws = (unsigned short*)((char*)d_ws + VWS_BYTES);
        unsigned short* PET = (unsigned short*)((char*)d_ws + VWS_BYTES + KWS_BYTES);
        pe_transpose_kernel<<<256, 256, 0, stream>>>(PE, PET);
        convK_kernel<<<6144, 256, 0, stream>>>(K, Kws);
        convV_kernel<<<dim3(24, 128), 256, 0, stream>>>(V, Vws);
        attn_v2<<<1024, 256, 0, stream>>>(Q, Kws, Vws, PET, SPAN, (float*)d_out);
    } else {
        unsigned short* PET = (unsigned short*)d_ws;
        pe_transpose_kernel<<<256, 256, 0, stream>>>(PE, PET);
        attn_v1<<<1024, 256, 0, stream>>>(Q, K, V, PET, SPAN, (float*)d_out);
    }
}